// Round 1
// baseline (8267.679 us; speedup 1.0000x reference)
//
#include <hip/hip_runtime.h>
#include <math.h>

#define T 512
#define B 128
#define E 256
#define H 256
#define G 1024   // 4H
#define DA 25
#define HEADS 5
#define NEGINF (-1e30f)

// ---------------- workspace layout (bytes) ----------------
// wt    : [2][256][1024] f32  (W_hh transposed, per dir)      2,097,152
// ws1t  : [512][25]      f32  (W_s1 transposed)                  51,200
// pxc   : [2][64][128][1024] f32 (chunk of gate preacts)     67,108,864
// hc    : [128][512][512] f32 (concat h_fwd|h_bwd)          134,217,728
// hstate: [2][128][256] f32                                     262,144
// cstate: [2][128][256] f32                                     262,144
// A     : [128][5][512] f32 (logits -> softmax in place)      1,310,720
// part  : [128] f32                                                 512
static constexpr size_t WT_OFF   = 0;
static constexpr size_t WS1T_OFF = 2097152;
static constexpr size_t PX_OFF   = 2148352;
static constexpr size_t HC_OFF   = 69257216;
static constexpr size_t HST_OFF  = 203474944;
static constexpr size_t CST_OFF  = 203737088;
static constexpr size_t A_OFF    = 203999232;
static constexpr size_t PART_OFF = 205309952;

__device__ __forceinline__ float sigmoidf_(float x) { return 1.f / (1.f + expf(-x)); }

// ---------------- prep: transpose W_hh (both dirs) and W_s1 ----------------
__global__ __launch_bounds__(256) void prep_kernel(const float* __restrict__ Whf,
                                                   const float* __restrict__ Whb,
                                                   const float* __restrict__ Ws1,
                                                   float* __restrict__ wt,
                                                   float* __restrict__ ws1t) {
    int idx = blockIdx.x * 256 + threadIdx.x;
    if (idx < 2 * G * H) {                       // 524288
        int d = idx >> 18;
        int rem = idx & 262143;
        int r = rem >> 8;                        // gate row 0..1023
        int k = rem & 255;                       // h index 0..255
        const float* W = d ? Whb : Whf;
        wt[(size_t)d * (G * H) + (size_t)k * G + r] = W[(size_t)r * H + k];
    }
    if (idx < DA * 512) {                        // 12800
        int r = idx / 512, k = idx % 512;
        ws1t[k * DA + r] = Ws1[idx];
    }
}

// ---------------- input projection for one 64-step chunk ----------------
// grid (16 gtiles, 128 b, 2 dir), block 256. Computes
// pxc[d][t-t0][b][g] = emb[wid(b,t,d)] . W_ih_d[g,:] + bias_d[g]
__global__ __launch_bounds__(256) void proj_kernel(const int* __restrict__ word_ids,
                                                   const int* __restrict__ lengths,
                                                   const float* __restrict__ emb,
                                                   const float* __restrict__ Wf,
                                                   const float* __restrict__ Wb,
                                                   const float* __restrict__ bf,
                                                   const float* __restrict__ bb,
                                                   float* __restrict__ pxc, int chunk) {
    int g0 = blockIdx.x * 64;
    int b  = blockIdx.y;
    int d  = blockIdx.z;
    int len = lengths[b];
    int t0 = chunk * 64;
    if (t0 >= len) return;
    const float* Wih  = d ? Wb : Wf;
    const float* bias = d ? bb : bf;

    __shared__ int   wid[64];
    __shared__ float As[16][65];
    __shared__ float Bs[16][65];

    int tid = threadIdx.x;
    if (tid < 64) {
        int t = t0 + tid;
        int src;
        if (d == 0) src = t;
        else { src = len - 1 - t; if (src < 0) src = 0; }
        wid[tid] = word_ids[b * T + src];
    }
    __syncthreads();

    int tx = tid & 15, ty = tid >> 4;   // compute mapping
    int kk = tid & 15, r0 = tid >> 4;   // load mapping
    float acc[4][4];
    #pragma unroll
    for (int i = 0; i < 4; i++)
        #pragma unroll
        for (int j = 0; j < 4; j++) acc[i][j] = 0.f;

    for (int k0 = 0; k0 < E; k0 += 16) {
        #pragma unroll
        for (int i = 0; i < 4; i++) {
            int m = r0 + 16 * i;
            As[kk][m] = emb[(size_t)wid[m] * E + k0 + kk];
            Bs[kk][m] = Wih[(size_t)(g0 + m) * E + k0 + kk];
        }
        __syncthreads();
        #pragma unroll
        for (int kq = 0; kq < 16; kq++) {
            float a[4], bv[4];
            #pragma unroll
            for (int i = 0; i < 4; i++) a[i] = As[kq][ty * 4 + i];
            #pragma unroll
            for (int j = 0; j < 4; j++) bv[j] = Bs[kq][tx * 4 + j];
            #pragma unroll
            for (int i = 0; i < 4; i++)
                #pragma unroll
                for (int j = 0; j < 4; j++) acc[i][j] += a[i] * bv[j];
        }
        __syncthreads();
    }
    #pragma unroll
    for (int i = 0; i < 4; i++) {
        int m = ty * 4 + i;
        #pragma unroll
        for (int j = 0; j < 4; j++) {
            int n = tx * 4 + j;
            pxc[((size_t)(d * 64 + m) * B + b) * G + g0 + n] = acc[i][j] + bias[g0 + n];
        }
    }
}

// ---------------- LSTM recurrence for one 64-step chunk ----------------
// grid (128 b, 2 dir), block 256 (thread j owns h[j], c[j])
__global__ __launch_bounds__(256) void lstm_chunk_kernel(const int* __restrict__ lengths,
                                                         const float* __restrict__ wt,
                                                         const float* __restrict__ pxc,
                                                         float* __restrict__ hc_out,
                                                         float* __restrict__ hstate,
                                                         float* __restrict__ cstate, int chunk) {
    int b = blockIdx.x, d = blockIdx.y;
    int len = lengths[b];
    int t0 = chunk * 64;
    if (t0 >= len) return;
    int tend = min(len, t0 + 64);
    int j = threadIdx.x;

    __shared__ float hs[H];
    float h, c;
    if (chunk == 0) { h = 0.f; c = 0.f; }
    else {
        h = hstate[((size_t)d * B + b) * H + j];
        c = cstate[((size_t)d * B + b) * H + j];
    }
    hs[j] = h;
    __syncthreads();

    const float* wtd = wt + (size_t)d * (G * H);
    for (int t = t0; t < tend; t++) {
        const float* px = pxc + ((size_t)(d * 64 + (t - t0)) * B + b) * G;
        float a0 = px[j], a1 = px[H + j], a2 = px[2 * H + j], a3 = px[3 * H + j];
        #pragma unroll 4
        for (int k = 0; k < H; k++) {
            float hk = hs[k];
            const float* wr = wtd + (size_t)k * G;
            a0 += wr[j]         * hk;
            a1 += wr[H + j]     * hk;
            a2 += wr[2 * H + j] * hk;
            a3 += wr[3 * H + j] * hk;
        }
        float ig = sigmoidf_(a0);
        float fg = sigmoidf_(a1);
        float og = sigmoidf_(a3);
        c = fg * c + ig * tanhf(a2);
        h = og * tanhf(c);
        __syncthreads();          // everyone done reading hs for step t
        hs[j] = h;
        int pos = d ? (len - 1 - t) : t;
        hc_out[((size_t)b * T + pos) * (2 * H) + d * H + j] = h;
        __syncthreads();          // hs ready for step t+1
    }
    hstate[((size_t)d * B + b) * H + j] = h;
    cstate[((size_t)d * B + b) * H + j] = c;
}

// ---------------- attention logits (masked) ----------------
// grid (8 tchunks, 128 b), block 256 = 4 waves, each wave does 16 timesteps
__global__ __launch_bounds__(256) void logits_kernel(const int* __restrict__ lengths,
                                                     const float* __restrict__ hc,
                                                     const float* __restrict__ ws1t,
                                                     const float* __restrict__ Ws2,
                                                     float* __restrict__ S) {
    __shared__ float s_w1[512 * DA];
    __shared__ float s_w2[HEADS * DA];
    int b = blockIdx.y, tt = blockIdx.x;
    int tid = threadIdx.x;
    for (int i = tid; i < 512 * DA; i += 256) s_w1[i] = ws1t[i];
    for (int i = tid; i < HEADS * DA; i += 256) s_w2[i] = Ws2[i];
    __syncthreads();

    int len = lengths[b];
    int lane = tid & 63, wave = tid >> 6;
    for (int ti = 0; ti < 16; ti++) {
        int t = tt * 64 + wave * 16 + ti;
        if (t < len) {
            float y[DA];
            #pragma unroll
            for (int r = 0; r < DA; r++) y[r] = 0.f;
            const float* hcp = hc + ((size_t)b * T + t) * (2 * H);
            #pragma unroll
            for (int kk = 0; kk < 8; kk++) {
                int k = lane + kk * 64;
                float v = hcp[k];
                const float* w = s_w1 + k * DA;
                #pragma unroll
                for (int r = 0; r < DA; r++) y[r] += v * w[r];
            }
            #pragma unroll
            for (int r = 0; r < DA; r++) {
                float v = y[r];
                for (int off = 32; off; off >>= 1) v += __shfl_xor(v, off, 64);
                y[r] = tanhf(v);
            }
            if (lane < HEADS) {
                float s = 0.f;
                #pragma unroll
                for (int r = 0; r < DA; r++) s += y[r] * s_w2[lane * DA + r];
                S[((size_t)b * HEADS + lane) * T + t] = s;
            }
        } else {
            if (lane < HEADS) S[((size_t)b * HEADS + lane) * T + t] = NEGINF;
        }
    }
}

// ---------------- masked softmax over T, in place ----------------
__global__ __launch_bounds__(256) void softmax_kernel(float* __restrict__ S) {
    int row = blockIdx.x;                      // b*5 + h
    float* p = S + (size_t)row * T;
    int tid = threadIdx.x;
    int lane = tid & 63, wave = tid >> 6;
    __shared__ float rr[4], ss[4];

    float mx = NEGINF;
    #pragma unroll
    for (int i = 0; i < 2; i++) mx = fmaxf(mx, p[tid + i * 256]);
    for (int off = 32; off; off >>= 1) mx = fmaxf(mx, __shfl_xor(mx, off, 64));
    if (lane == 0) rr[wave] = mx;
    __syncthreads();
    mx = fmaxf(fmaxf(rr[0], rr[1]), fmaxf(rr[2], rr[3]));

    float e[2], sum = 0.f;
    #pragma unroll
    for (int i = 0; i < 2; i++) { e[i] = expf(p[tid + i * 256] - mx); sum += e[i]; }
    for (int off = 32; off; off >>= 1) sum += __shfl_xor(sum, off, 64);
    if (lane == 0) ss[wave] = sum;
    __syncthreads();
    sum = ss[0] + ss[1] + ss[2] + ss[3];
    float inv = 1.f / sum;
    #pragma unroll
    for (int i = 0; i < 2; i++) p[tid + i * 256] = e[i] * inv;
}

// ---------------- M = A @ Hc -> sentence embeddings (d_out) ----------------
__global__ __launch_bounds__(256) void attnM_kernel(const int* __restrict__ lengths,
                                                    const float* __restrict__ A,
                                                    const float* __restrict__ hc,
                                                    float* __restrict__ out) {
    int b = blockIdx.x, tid = threadIdx.x;
    int len = lengths[b];
    const float* Ab  = A + (size_t)b * HEADS * T;
    const float* hcb = hc + (size_t)b * T * (2 * H);
    float acc[HEADS][2];
    #pragma unroll
    for (int h = 0; h < HEADS; h++) { acc[h][0] = 0.f; acc[h][1] = 0.f; }
    for (int t = 0; t < len; t++) {
        float v0 = hcb[(size_t)t * (2 * H) + tid];
        float v1 = hcb[(size_t)t * (2 * H) + H + tid];
        #pragma unroll
        for (int h = 0; h < HEADS; h++) {
            float a = Ab[h * T + t];
            acc[h][0] += a * v0;
            acc[h][1] += a * v1;
        }
    }
    #pragma unroll
    for (int h = 0; h < HEADS; h++) {
        out[(size_t)b * (HEADS * 2 * H) + h * (2 * H) + tid]     = acc[h][0];
        out[(size_t)b * (HEADS * 2 * H) + h * (2 * H) + H + tid] = acc[h][1];
    }
}

// ---------------- penalization partials per sample ----------------
__global__ __launch_bounds__(256) void penal_kernel(const float* __restrict__ A,
                                                    float* __restrict__ part) {
    int b = blockIdx.x, tid = threadIdx.x;
    const float* Ab = A + (size_t)b * HEADS * T;
    float p[10];
    #pragma unroll
    for (int i = 0; i < 10; i++) p[i] = 0.f;
    for (int t = tid; t < T; t += 256) {
        float a0 = Ab[t], a1 = Ab[T + t], a2 = Ab[2 * T + t], a3 = Ab[3 * T + t], a4 = Ab[4 * T + t];
        p[0] += a0 * a1; p[1] += a0 * a2; p[2] += a0 * a3; p[3] += a0 * a4;
        p[4] += a1 * a2; p[5] += a1 * a3; p[6] += a1 * a4;
        p[7] += a2 * a3; p[8] += a2 * a4; p[9] += a3 * a4;
    }
    __shared__ float red[10][4];
    int lane = tid & 63, wave = tid >> 6;
    #pragma unroll
    for (int i = 0; i < 10; i++) {
        float v = p[i];
        for (int off = 32; off; off >>= 1) v += __shfl_xor(v, off, 64);
        if (lane == 0) red[i][wave] = v;
    }
    __syncthreads();
    if (tid == 0) {
        float s = 0.f;
        #pragma unroll
        for (int i = 0; i < 10; i++) {
            float P = red[i][0] + red[i][1] + red[i][2] + red[i][3];
            s += 2.f * P * P;   // symmetric off-diagonal
        }
        part[b] = s;
    }
}

__global__ __launch_bounds__(128) void final_kernel(const float* __restrict__ part,
                                                    float* __restrict__ out) {
    int tid = threadIdx.x;
    float v = part[tid];
    for (int off = 32; off; off >>= 1) v += __shfl_xor(v, off, 64);
    __shared__ float r2[2];
    if ((tid & 63) == 0) r2[tid >> 6] = v;
    __syncthreads();
    if (tid == 0) out[(size_t)B * HEADS * 2 * H] = (r2[0] + r2[1]) * (1.f / (float)B);
}

// ---------------- host launcher ----------------
extern "C" void kernel_launch(void* const* d_in, const int* in_sizes, int n_in,
                              void* d_out, int out_size, void* d_ws, size_t ws_size,
                              hipStream_t stream) {
    const int*   word_ids = (const int*)d_in[0];
    const int*   lengths  = (const int*)d_in[1];
    const float* emb      = (const float*)d_in[2];
    const float* W_ih_f   = (const float*)d_in[3];
    const float* W_hh_f   = (const float*)d_in[4];
    const float* b_f      = (const float*)d_in[5];
    const float* W_ih_b   = (const float*)d_in[6];
    const float* W_hh_b   = (const float*)d_in[7];
    const float* b_b      = (const float*)d_in[8];
    const float* W_s1     = (const float*)d_in[9];
    const float* W_s2     = (const float*)d_in[10];
    float* out = (float*)d_out;

    char* ws = (char*)d_ws;
    float* wt     = (float*)(ws + WT_OFF);
    float* ws1t   = (float*)(ws + WS1T_OFF);
    float* pxc    = (float*)(ws + PX_OFF);
    float* hc     = (float*)(ws + HC_OFF);
    float* hstate = (float*)(ws + HST_OFF);
    float* cstate = (float*)(ws + CST_OFF);
    float* Abuf   = (float*)(ws + A_OFF);
    float* part   = (float*)(ws + PART_OFF);

    prep_kernel<<<2048, 256, 0, stream>>>(W_hh_f, W_hh_b, W_s1, wt, ws1t);

    for (int c = 0; c < 8; c++) {
        proj_kernel<<<dim3(16, 128, 2), 256, 0, stream>>>(
            word_ids, lengths, emb, W_ih_f, W_ih_b, b_f, b_b, pxc, c);
        lstm_chunk_kernel<<<dim3(128, 2), 256, 0, stream>>>(
            lengths, wt, pxc, hc, hstate, cstate, c);
    }

    logits_kernel<<<dim3(8, 128), 256, 0, stream>>>(lengths, hc, ws1t, W_s2, Abuf);
    softmax_kernel<<<B * HEADS, 256, 0, stream>>>(Abuf);
    attnM_kernel<<<B, 256, 0, stream>>>(lengths, Abuf, hc, out);
    penal_kernel<<<B, 256, 0, stream>>>(Abuf, part);
    final_kernel<<<1, 128, 0, stream>>>(part, out);
}